// Round 8
// baseline (2240.117 us; speedup 1.0000x reference)
//
#include <hip/hip_runtime.h>
#include <stdint.h>

#define NN 8192
#define DD 128
#define ALPHA 0.7f
#define BETA 0.3f
#define LAM 0.1f
#define QSCALE 0.08838834764831845f  // 1/sqrt(128)
#define DELTA 3e-5f
#define FLAGCAP 262144

typedef __attribute__((ext_vector_type(8))) short short8;
typedef __attribute__((ext_vector_type(4))) float f32x4;
typedef unsigned short ush;

__device__ __forceinline__ ush f2bf(float f){
  union { float f; unsigned u; } v; v.f = f;
  return (ush)((v.u + 0x7FFFu + ((v.u >> 16) & 1u)) >> 16);
}
__device__ __forceinline__ float bf2f(ush s){
  union { unsigned u; float f; } v; v.u = ((unsigned)s) << 16; return v.f;
}

// ---------------- adjacency -> bitmask (one HBM pass; 8 MB output stays in L3) ----------------
__global__ void k_pack(const float* __restrict__ adj, unsigned* __restrict__ adjw){
  int i = blockIdx.x, wave = threadIdx.x >> 6, lane = threadIdx.x & 63;
  for (int seg = wave; seg < 128; seg += 4){
    int j = seg*64 + lane;
    unsigned long long bm = __ballot(adj[(size_t)i*NN + j] != 0.0f);
    if (lane == 0)  adjw[i*256 + seg*2]     = (unsigned)bm;
    if (lane == 32) adjw[i*256 + seg*2 + 1] = (unsigned)(bm >> 32);
  }
}

// ---------------- norms + normalized hi/lo + raw transposed hi/lo (merged) ----------------
__global__ void k_prep(const float* __restrict__ E, double* __restrict__ nrm64,
                       ush* __restrict__ Enh, ush* __restrict__ Enl,
                       ush* __restrict__ EhiT, ush* __restrict__ EloT){
  __shared__ float t[64*130];
  int tid = threadIdx.x;
  int r0 = blockIdx.x * 64;
  #pragma unroll
  for (int i = 0; i < 32; i++){
    int idx = tid + i*256;
    int r = idx >> 7, c = idx & 127;
    t[r*130 + c] = E[(r0 + r)*DD + c];
  }
  __syncthreads();
  int row = tid >> 2, part = tid & 3;
  double ss = 0.0;
  #pragma unroll
  for (int j = 0; j < 32; j++){
    float v = t[row*130 + part*32 + j];
    ss += (double)v*(double)v;
  }
  ss += __shfl_xor(ss, 1, 64);
  ss += __shfl_xor(ss, 2, 64);
  double nr = sqrt(ss); if (nr < 1e-8) nr = 1e-8;
  float inv = (float)(1.0 / nr);
  if (part == 0) nrm64[r0 + row] = nr;
  // normalized hi/lo, row-major (coalesced uint4 stores)
  {
    ush nh[32], nl[32];
    #pragma unroll
    for (int j = 0; j < 32; j++){
      float n = t[row*130 + part*32 + j] * inv;
      ush h = f2bf(n);
      nh[j] = h; nl[j] = f2bf(n - bf2f(h));
    }
    size_t ro = (size_t)(r0 + row)*DD + part*32;
    #pragma unroll
    for (int j = 0; j < 4; j++){
      *(uint4*)&Enh[ro + j*8] = *(const uint4*)&nh[j*8];
      *(uint4*)&Enl[ro + j*8] = *(const uint4*)&nl[j*8];
    }
  }
  // raw hi/lo, transposed [128][8192]
  {
    int col = tid >> 1, rh = (tid & 1)*32;
    ush hh[32], ll[32];
    #pragma unroll
    for (int j = 0; j < 32; j++){
      float v = t[(rh + j)*130 + col];
      ush h = f2bf(v);
      hh[j] = h; ll[j] = f2bf(v - bf2f(h));
    }
    size_t go = (size_t)col*NN + r0 + rh;
    #pragma unroll
    for (int j = 0; j < 4; j++){
      *(uint4*)&EhiT[go + j*8] = *(const uint4*)&hh[j*8];
      *(uint4*)&EloT[go + j*8] = *(const uint4*)&ll[j*8];
    }
  }
}

// ---------------- all weight transposes+splits in one dispatch ----------------
__global__ void k_transw_all(const float* __restrict__ wq, const float* __restrict__ wk,
                             const float* __restrict__ wv, const float* __restrict__ g1w,
                             const float* __restrict__ gcw,
                             ush* __restrict__ qkvTh, ush* __restrict__ qkvTl,
                             ush* __restrict__ g1wTh, ush* __restrict__ g1wTl,
                             ush* __restrict__ gcwTh, ush* __restrict__ gcwTl){
  int idx = blockIdx.x*256 + threadIdx.x;
  const float* src; ush *dh, *dl; int K, Nout, li;
  if      (idx <  16384){ src=wq;        dh=qkvTh;        dl=qkvTl;        K=128; Nout=128; li=idx; }
  else if (idx <  32768){ src=wk;        dh=qkvTh+16384;  dl=qkvTl+16384;  K=128; Nout=128; li=idx-16384; }
  else if (idx <  49152){ src=wv;        dh=qkvTh+32768;  dl=qkvTl+32768;  K=128; Nout=128; li=idx-32768; }
  else if (idx < 180224){ src=g1w;       dh=g1wTh;        dl=g1wTl;        K=512; Nout=256; li=idx-49152; }
  else if (idx < 196608){ src=gcw;       dh=gcwTh;        dl=gcwTl;        K=128; Nout=128; li=idx-180224; }
  else if (idx < 212992){ src=gcw+16384; dh=gcwTh+16384;  dl=gcwTl+16384;  K=128; Nout=128; li=idx-196608; }
  else return;
  int k = li / Nout, n = li - k*Nout;
  float v = src[li];
  ush h = f2bf(v);
  dh[n*K + k] = h;
  dl[n*K + k] = f2bf(v - bf2f(h));
}

// ---------------- fused Q/K/V projection; V written transposed+split via LDS ----------------
__global__ void k_qkv(const float* __restrict__ A,
                      const ush* __restrict__ BtH, const ush* __restrict__ BtL,
                      const float* __restrict__ bq, const float* __restrict__ bk,
                      const float* __restrict__ bv,
                      ush* __restrict__ Qh, ush* __restrict__ Kh,
                      ush* __restrict__ VhT, ush* __restrict__ VloT){
  __shared__ float sV[128*33];
  int tid = threadIdx.x, lane = tid & 63, wave = tid >> 6;
  int l15 = lane & 15, quad = lane >> 4;
  int rowblk = blockIdx.x * 32;
  int row16 = rowblk + (wave >> 1)*16;
  int nf0 = (wave & 1)*12;
  f32x4 acc[12];
  #pragma unroll
  for (int i = 0; i < 12; i++){ f32x4 z = {0.f,0.f,0.f,0.f}; acc[i] = z; }
  #pragma unroll
  for (int kk = 0; kk < 4; kk++){
    const float* ap = &A[(row16 + l15)*DD + kk*32 + quad*8];
    short8 ah, al;
    #pragma unroll
    for (int j = 0; j < 8; j++){
      float v = ap[j];
      ush h = f2bf(v);
      ah[j] = (short)h; al[j] = (short)f2bf(v - bf2f(h));
    }
    #pragma unroll
    for (int i = 0; i < 12; i++){
      int bo = ((nf0 + i)*16 + l15)*DD + kk*32 + quad*8;
      short8 bh = *(const short8*)&BtH[bo];
      short8 bl = *(const short8*)&BtL[bo];
      acc[i] = __builtin_amdgcn_mfma_f32_16x16x32_bf16(ah, bh, acc[i], 0, 0, 0);
      acc[i] = __builtin_amdgcn_mfma_f32_16x16x32_bf16(al, bh, acc[i], 0, 0, 0);
      acc[i] = __builtin_amdgcn_mfma_f32_16x16x32_bf16(ah, bl, acc[i], 0, 0, 0);
    }
  }
  #pragma unroll
  for (int i = 0; i < 12; i++){
    int nfg = nf0 + i;
    int grp = nfg >> 3;
    int col = (nfg & 7)*16 + l15;
    float b = (grp == 0) ? bq[col] : (grp == 1) ? bk[col] : bv[col];
    #pragma unroll
    for (int r = 0; r < 4; r++){
      int row = row16 + quad*4 + r;
      float v = acc[i][r] + b;
      if (grp == 0)      Qh[row*DD + col] = f2bf(v * QSCALE);
      else if (grp == 1) Kh[row*DD + col] = f2bf(v);
      else               sV[col*33 + (row - rowblk)] = v;
    }
  }
  __syncthreads();
  int feat = tid >> 1, rh = (tid & 1)*16;
  ush hh[16], ll[16];
  #pragma unroll
  for (int j = 0; j < 16; j++){
    float v = sV[feat*33 + rh + j];
    ush h = f2bf(v);
    hh[j] = h; ll[j] = f2bf(v - bf2f(h));
  }
  size_t go = (size_t)feat*NN + rowblk + rh;
  *(uint4*)&VhT [go]     = *(const uint4*)&hh[0];
  *(uint4*)&VhT [go + 8] = *(const uint4*)&hh[8];
  *(uint4*)&VloT[go]     = *(const uint4*)&ll[0];
  *(uint4*)&VloT[go + 8] = *(const uint4*)&ll[8];
}

// ---------------- g1 GEMM with inline region scaling (2x2 wave split) ----------------
__global__ void k_g1(const float* __restrict__ E, const float* __restrict__ P,
                     const float* __restrict__ B, const float* __restrict__ N,
                     const float* __restrict__ cntP, const float* __restrict__ cntN,
                     const float* __restrict__ denB,
                     const ush* __restrict__ BtH, const ush* __restrict__ BtL,
                     const float* __restrict__ bias, float* __restrict__ out){
  int tid = threadIdx.x, lane = tid & 63, wave = tid >> 6;
  int l15 = lane & 15, quad = lane >> 4;
  int row16 = blockIdx.x*32 + (wave >> 1)*16;
  int nf0 = (wave & 1)*8;
  int row = row16 + l15;
  float cp = cntP[row], cn = cntN[row], dn = denB[row];
  float rs[4] = {1.f, 1.f/fmaxf(cp,1.f), (dn > 0.5f) ? (1.f/dn) : 0.f, LAM/fmaxf(cn,1.f)};
  const float* bases[4] = {E, P, B, N};
  f32x4 acc[8];
  #pragma unroll
  for (int nf = 0; nf < 8; nf++){ f32x4 z = {0.f,0.f,0.f,0.f}; acc[nf] = z; }
  #pragma unroll
  for (int kk = 0; kk < 16; kk++){
    const float* ap = &bases[kk>>2][row*DD + (kk&3)*32 + quad*8];
    float sc = rs[kk>>2];
    short8 ah, al;
    #pragma unroll
    for (int j = 0; j < 8; j++){
      float v = ap[j] * sc;
      ush h = f2bf(v);
      ah[j] = (short)h; al[j] = (short)f2bf(v - bf2f(h));
    }
    #pragma unroll
    for (int nf = 0; nf < 8; nf++){
      int bo = ((nf0 + nf)*16 + l15)*512 + kk*32 + quad*8;
      short8 bh = *(const short8*)&BtH[bo];
      short8 bl = *(const short8*)&BtL[bo];
      acc[nf] = __builtin_amdgcn_mfma_f32_16x16x32_bf16(ah, bh, acc[nf], 0, 0, 0);
      acc[nf] = __builtin_amdgcn_mfma_f32_16x16x32_bf16(al, bh, acc[nf], 0, 0, 0);
      acc[nf] = __builtin_amdgcn_mfma_f32_16x16x32_bf16(ah, bl, acc[nf], 0, 0, 0);
    }
  }
  #pragma unroll
  for (int nf = 0; nf < 8; nf++){
    int col = (nf0 + nf)*16 + l15;
    float b = bias[col];
    #pragma unroll
    for (int r = 0; r < 4; r++){
      int rr = row16 + quad*4 + r;
      out[rr*256 + col] = fmaxf(acc[nf][r] + b, 0.f);
    }
  }
}

// ---------------- fused gate + fusion + gc GEMM (+ optional final combine) ----------------
__global__ void k_fusegc(const float* __restrict__ E, const float* __restrict__ P,
                         const float* __restrict__ B, const float* __restrict__ N,
                         const float* __restrict__ hbuf, const float* __restrict__ g2w,
                         const float* __restrict__ g2b,
                         const float* __restrict__ cntP, const float* __restrict__ cntN,
                         const float* __restrict__ denB,
                         const ush* __restrict__ BtH, const ush* __restrict__ BtL,
                         const float* __restrict__ bias,
                         const float* __restrict__ prevC, const float* __restrict__ lwv,
                         int dofinal, float* __restrict__ out){
  int tid = threadIdx.x, lane = tid & 63, wave = tid >> 6;
  int l15 = lane & 15, quad = lane >> 4;
  int row16 = blockIdx.x*32 + (wave >> 1)*16;
  int nf0 = (wave & 1)*4;
  int row = row16 + l15;
  float l0=0,l1=0,l2=0,l3=0;
  #pragma unroll
  for (int i = 0; i < 16; i++){
    float4 hv = *(const float4*)&hbuf[row*256 + quad*64 + i*4];
    float hvv[4] = {hv.x, hv.y, hv.z, hv.w};
    #pragma unroll
    for (int j = 0; j < 4; j++){
      float4 w4 = *(const float4*)&g2w[(quad*64 + i*4 + j)*4];
      l0 = fmaf(hvv[j], w4.x, l0); l1 = fmaf(hvv[j], w4.y, l1);
      l2 = fmaf(hvv[j], w4.z, l2); l3 = fmaf(hvv[j], w4.w, l3);
    }
  }
  l0 += __shfl_xor(l0,16,64); l0 += __shfl_xor(l0,32,64);
  l1 += __shfl_xor(l1,16,64); l1 += __shfl_xor(l1,32,64);
  l2 += __shfl_xor(l2,16,64); l2 += __shfl_xor(l2,32,64);
  l3 += __shfl_xor(l3,16,64); l3 += __shfl_xor(l3,32,64);
  l0 += g2b[0]; l1 += g2b[1]; l2 += g2b[2]; l3 += g2b[3];
  float mx = fmaxf(fmaxf(l0,l1), fmaxf(l2,l3));
  float e0 = __expf(l0-mx), e1 = __expf(l1-mx), e2 = __expf(l2-mx), e3 = __expf(l3-mx);
  float inv = 1.f/(e0+e1+e2+e3);
  float g0 = e0*inv, g1v = e1*inv, g2v = e2*inv, g3 = e3*inv;
  float cp = cntP[row], cn = cntN[row], dn = denB[row];
  bool any = (cp + cn > 0.5f) || (dn > 0.5f);
  float pscl = g1v/fmaxf(cp,1.f);
  float bscl = (dn > 0.5f) ? (g2v/dn) : 0.f;
  float nscl = LAM*g3/fmaxf(cn,1.f);
  f32x4 acc[4];
  #pragma unroll
  for (int nf = 0; nf < 4; nf++){ f32x4 z = {0.f,0.f,0.f,0.f}; acc[nf] = z; }
  #pragma unroll
  for (int kk = 0; kk < 4; kk++){
    int koff = row*DD + kk*32 + quad*8;
    short8 ah, al;
    #pragma unroll
    for (int j = 0; j < 8; j++){
      float ev = E[koff + j];
      float v = any ? (g0*ev + pscl*P[koff+j] + bscl*B[koff+j] + nscl*N[koff+j]) : ev;
      ush h = f2bf(v);
      ah[j] = (short)h; al[j] = (short)f2bf(v - bf2f(h));
    }
    #pragma unroll
    for (int nf = 0; nf < 4; nf++){
      int bo = ((nf0 + nf)*16 + l15)*DD + kk*32 + quad*8;
      short8 bh = *(const short8*)&BtH[bo];
      short8 bl = *(const short8*)&BtL[bo];
      acc[nf] = __builtin_amdgcn_mfma_f32_16x16x32_bf16(ah, bh, acc[nf], 0, 0, 0);
      acc[nf] = __builtin_amdgcn_mfma_f32_16x16x32_bf16(al, bh, acc[nf], 0, 0, 0);
      acc[nf] = __builtin_amdgcn_mfma_f32_16x16x32_bf16(ah, bl, acc[nf], 0, 0, 0);
    }
  }
  float we0 = 0.5f, we1 = 0.5f;
  if (dofinal){
    float a0 = lwv[0], a1 = lwv[1];
    float mw = fmaxf(a0, a1);
    float x0 = __expf(a0-mw), x1 = __expf(a1-mw);
    float iv = 1.f/(x0+x1);
    we0 = x0*iv; we1 = x1*iv;
  }
  #pragma unroll
  for (int nf = 0; nf < 4; nf++){
    int col = (nf0 + nf)*16 + l15;
    float b = bias[col];
    #pragma unroll
    for (int r = 0; r < 4; r++){
      int rr = row16 + quad*4 + r;
      float val = fmaxf(acc[nf][r] + b, 0.f);
      if (dofinal) val = we0*prevC[rr*DD + col] + we1*val;
      out[rr*DD + col] = val;
    }
  }
}

// ---------------- fused sim/classify/aggregate ----------------
// Staging/prefetch structure = R6/R7 (cache-proven). LDS strides = R4 (conflict-free,
// correctness-proven): separate hi/lo arrays at 40-short stride (20 dw == 20 mod 32
// -> b128 reads hit all 8 bank-groups; only the free 2-way l/l+8 alias remains).
#define BM 64
#define BN 32
#define CSPLIT 4
#define CCHUNK (NN/CSPLIT)
#define NTILES (CCHUNK/BN)
#define RSTRIDE 136
#define FS 40
#define MS 40

__launch_bounds__(256, 2)
__global__ void k_fused(const unsigned* __restrict__ adjw,
    const ush* __restrict__ Enh, const ush* __restrict__ Enl,
    const ush* __restrict__ Qh,  const ush* __restrict__ Kh,
    const ush* __restrict__ EhiT, const ush* __restrict__ EloT,
    const ush* __restrict__ VhT,  const ush* __restrict__ VloT,
    float* __restrict__ Psum, float* __restrict__ Nsum, float* __restrict__ Bsum,
    float* __restrict__ cntP, float* __restrict__ cntN, float* __restrict__ denB,
    int* __restrict__ flagCnt, float4* __restrict__ flags)
{
  __shared__ __attribute__((aligned(16))) ush sEnh[32*RSTRIDE];
  __shared__ __attribute__((aligned(16))) ush sEnl[32*RSTRIDE];
  __shared__ __attribute__((aligned(16))) ush sKh [32*RSTRIDE];
  __shared__ __attribute__((aligned(16))) ush sE2h[128*FS];
  __shared__ __attribute__((aligned(16))) ush sE2l[128*FS];
  __shared__ __attribute__((aligned(16))) ush sV2h[128*FS];
  __shared__ __attribute__((aligned(16))) ush sV2l[128*FS];
  __shared__ __attribute__((aligned(16))) ush sMa[4][16*MS];
  __shared__ __attribute__((aligned(16))) ush sMb[4][16*MS];

  int tid = threadIdx.x, lane = tid & 63, wave = tid >> 6;
  int l15 = lane & 15, quad = lane >> 4;
  int rowblk = blockIdx.x >> 2, split = blockIdx.x & 3;
  int row0 = rowblk * BM + wave * 16;
  int col0 = split * CCHUNK;

  short8 bEnh[4], bEnl[4], bQ[4];
  #pragma unroll
  for (int kf = 0; kf < 4; kf++){
    int go = (row0 + l15)*DD + kf*32 + quad*8;
    bEnh[kf] = *(const short8*)&Enh[go];
    bEnl[kf] = *(const short8*)&Enl[go];
    bQ  [kf] = *(const short8*)&Qh [go];
  }

  f32x4 accP[8], accN[8], accB[8];
  #pragma unroll
  for (int nf = 0; nf < 8; nf++){ f32x4 z = {0.f,0.f,0.f,0.f}; accP[nf]=z; accN[nf]=z; accB[nf]=z; }
  float cpL = 0.f, cnL = 0.f, dbL = 0.f;

  int f0 = tid >> 2,        n0 = (tid & 3)*8;
  int f1 = (tid+256) >> 2,  n1 = ((tid+256) & 3)*8;
  uint4 pEh0, pEh1, pEl0, pEl1, pVh0, pVh1, pVl0, pVl1;
  {
    size_t g0 = (size_t)f0*NN + col0 + n0, g1 = (size_t)f1*NN + col0 + n1;
    pEh0 = *(const uint4*)&EhiT[g0]; pEh1 = *(const uint4*)&EhiT[g1];
    pEl0 = *(const uint4*)&EloT[g0]; pEl1 = *(const uint4*)&EloT[g1];
    pVh0 = *(const uint4*)&VhT [g0]; pVh1 = *(const uint4*)&VhT [g1];
    pVl0 = *(const uint4*)&VloT[g0]; pVl1 = *(const uint4*)&VloT[g1];
  }
  int rr0 = tid >> 4,       ro0 = (tid & 15)*8;
  int rr1 = (tid+256) >> 4, ro1 = ((tid+256) & 15)*8;

  for (int t = 0; t < NTILES; t++){
    int c0 = col0 + t*BN;
    __syncthreads();
    *(uint4*)&sE2h[f0*FS + n0] = pEh0;  *(uint4*)&sE2h[f1*FS + n1] = pEh1;
    *(uint4*)&sE2l[f0*FS + n0] = pEl0;  *(uint4*)&sE2l[f1*FS + n1] = pEl1;
    *(uint4*)&sV2h[f0*FS + n0] = pVh0;  *(uint4*)&sV2h[f1*FS + n1] = pVh1;
    *(uint4*)&sV2l[f0*FS + n0] = pVl0;  *(uint4*)&sV2l[f1*FS + n1] = pVl1;
    {
      uint4 a0 = *(const uint4*)&Enh[(c0 + rr0)*DD + ro0];
      uint4 a1 = *(const uint4*)&Enh[(c0 + rr1)*DD + ro1];
      uint4 b0 = *(const uint4*)&Enl[(c0 + rr0)*DD + ro0];
      uint4 b1 = *(const uint4*)&Enl[(c0 + rr1)*DD + ro1];
      uint4 k0 = *(const uint4*)&Kh [(c0 + rr0)*DD + ro0];
      uint4 k1 = *(const uint4*)&Kh [(c0 + rr1)*DD + ro1];
      *(uint4*)&sEnh[rr0*RSTRIDE + ro0] = a0;  *(uint4*)&sEnh[rr1*RSTRIDE + ro1] = a1;
      *(uint4*)&sEnl[rr0*RSTRIDE + ro0] = b0;  *(uint4*)&sEnl[rr1*RSTRIDE + ro1] = b1;
      *(uint4*)&sKh [rr0*RSTRIDE + ro0] = k0;  *(uint4*)&sKh [rr1*RSTRIDE + ro1] = k1;
    }
    __syncthreads();
    if (t + 1 < NTILES){
      int c1 = c0 + BN;
      size_t g0 = (size_t)f0*NN + c1 + n0, g1 = (size_t)f1*NN + c1 + n1;
      pEh0 = *(const uint4*)&EhiT[g0]; pEh1 = *(const uint4*)&EhiT[g1];
      pEl0 = *(const uint4*)&EloT[g0]; pEl1 = *(const uint4*)&EloT[g1];
      pVh0 = *(const uint4*)&VhT [g0]; pVh1 = *(const uint4*)&VhT [g1];
      pVl0 = *(const uint4*)&VloT[g0]; pVl1 = *(const uint4*)&VloT[g1];
    }
    unsigned aw = adjw[(row0 + l15)*256 + (c0 >> 5)];

    f32x4 simT[2], svT[2];
    { f32x4 z = {0.f,0.f,0.f,0.f}; simT[0]=z; simT[1]=z; svT[0]=z; svT[1]=z; }
    #pragma unroll
    for (int f = 0; f < 2; f++){
      #pragma unroll
      for (int kf = 0; kf < 4; kf++){
        int la = (f*16 + l15)*RSTRIDE + kf*32 + quad*8;
        short8 ch = *(const short8*)&sEnh[la];
        short8 cl = *(const short8*)&sEnl[la];
        short8 ck = *(const short8*)&sKh [la];
        simT[f] = __builtin_amdgcn_mfma_f32_16x16x32_bf16(ch, bEnh[kf], simT[f],0,0,0);
        simT[f] = __builtin_amdgcn_mfma_f32_16x16x32_bf16(cl, bEnh[kf], simT[f],0,0,0);
        simT[f] = __builtin_amdgcn_mfma_f32_16x16x32_bf16(ch, bEnl[kf], simT[f],0,0,0);
        svT [f] = __builtin_amdgcn_mfma_f32_16x16x32_bf16(ck, bQ  [kf], svT [f],0,0,0);
      }
    }
    ushort4 ehv[2], elv[2];
    unsigned flagb = 0;
    #pragma unroll
    for (int f = 0; f < 2; f++){
      ush vp[4], vn2[4], veh[4], vel[4];
      #pragma unroll
      for (int r = 0; r < 4; r++){
        int cbit = f*16 + quad*4 + r;
        bool nbr = (aw >> cbit) & 1u;
        float c = simT[f][r], s = svT[f][r];
        bool pos = nbr && (c >= ALPHA);
        bool neg = nbr && (c <= BETA);
        bool bnd = nbr && !pos && !neg;
        float e = bnd ? __expf(s) : 0.f;
        ush eh = f2bf(e);
        vp[r]  = pos ? (ush)0x3F80 : (ush)0;
        vn2[r] = neg ? (ush)0x3F80 : (ush)0;
        veh[r] = eh;
        vel[r] = f2bf(e - bf2f(eh));
        cpL += pos ? 1.f : 0.f;
        cnL += neg ? 1.f : 0.f;
        dbL += e;
        if (nbr && (fabsf(c - ALPHA) < DELTA || fabsf(c - BETA) < DELTA))
          flagb |= 1u << (f*4 + r);
      }
      int mb = l15*MS + f*16 + quad*4;
      *(ushort4*)&sMa[wave][mb] = make_ushort4(vp[0],vp[1],vp[2],vp[3]);
      *(ushort4*)&sMb[wave][mb] = make_ushort4(vn2[0],vn2[1],vn2[2],vn2[3]);
      ehv[f] = make_ushort4(veh[0],veh[1],veh[2],veh[3]);
      elv[f] = make_ushort4(vel[0],vel[1],vel[2],vel[3]);
    }
    if (__ballot(flagb != 0)){
      #pragma unroll
      for (int f = 0; f < 2; f++){
        #pragma unroll
        for (int r = 0; r < 4; r++){
          bool fl = (flagb >> (f*4 + r)) & 1u;
          unsigned long long bm = __ballot(fl);
          if (bm){
            int leader = __ffsll((long long)bm) - 1;
            int base = 0;
            if (lane == leader) base = atomicAdd(flagCnt, __popcll(bm));
            base = __shfl(base, leader, 64);
            if (fl){
              int id = base + __popcll(bm & ((1ull << lane) - 1ull));
              if (id < FLAGCAP){
                float4 rec;
                rec.x = __int_as_float(row0 + l15);
                rec.y = __int_as_float(c0 + f*16 + quad*4 + r);
                rec.z = simT[f][r]; rec.w = svT[f][r];
                flags[id] = rec;
              }
            }
          }
        }
      }
    }
    // phase A: P/N accumulation
    {
      short8 mPos = *(const short8*)&sMa[wave][l15*MS + quad*8];
      short8 mNeg = *(const short8*)&sMb[wave][l15*MS + quad*8];
      #pragma unroll
      for (int nf = 0; nf < 8; nf++){
        int so = (nf*16 + l15)*FS + quad*8;
        short8 eth = *(const short8*)&sE2h[so];
        short8 etl = *(const short8*)&sE2l[so];
        accP[nf] = __builtin_amdgcn_mfma_f32_16x16x32_bf16(mPos, eth, accP[nf],0,0,0);
        accP[nf] = __builtin_amdgcn_mfma_f32_16x16x32_bf16(mPos, etl, accP[nf],0,0,0);
        accN[nf] = __builtin_amdgcn_mfma_f32_16x16x32_bf16(mNeg, eth, accN[nf],0,0,0);
        accN[nf] = __builtin_amdgcn_mfma_f32_16x16x32_bf16(mNeg, etl, accN[nf],0,0,0);
      }
    }
    // phase B: overwrite masks with e hi/lo (same-wave DS in-order), accumulate B
    {
      int mb0 = l15*MS + quad*4;
      *(ushort4*)&sMa[wave][mb0]      = ehv[0];
      *(ushort4*)&sMa[wave][mb0 + 16] = ehv[1];
      *(ushort4*)&sMb[wave][mb0]      = elv[0];
      *(ushort4*)&sMb[wave][mb0 + 16] = elv[1];
      short8 mEh = *(const short8*)&sMa[wave][l15*MS + quad*8];
      short8 mEl = *(const short8*)&sMb[wave][l15*MS + quad*8];
      #pragma unroll
      for (int nf = 0; nf < 8; nf++){
        int so = (nf*16 + l15)*FS + quad*8;
        short8 vth = *(const short8*)&sV2h[so];
        short8 vtl = *(const short8*)&sV2l[so];
        accB[nf] = __builtin_amdgcn_mfma_f32_16x16x32_bf16(mEh, vth, accB[nf],0,0,0);
        accB[nf] = __builtin_amdgcn_mfma_f32_16x16x32_bf16(mEl, vth, accB[nf],0,0,0);
        accB[nf] = __builtin_amdgcn_mfma_f32_16x16x32_bf16(mEh, vtl, accB[nf],0,0,0);
      }
    }
  }
  #pragma unroll
  for (int nf = 0; nf < 8; nf++){
    int col = nf*16 + l15;
    #pragma unroll
    for (int r = 0; r < 4; r++){
      int row = row0 + quad*4 + r;
      atomicAdd(&Psum[row*DD + col], accP[nf][r]);
      atomicAdd(&Nsum[row*DD + col], accN[nf][r]);
      atomicAdd(&Bsum[row*DD + col], accB[nf][r]);
    }
  }
  cpL += __shfl_xor(cpL, 16, 64); cpL += __shfl_xor(cpL, 32, 64);
  cnL += __shfl_xor(cnL, 16, 64); cnL += __shfl_xor(cnL, 32, 64);
  dbL += __shfl_xor(dbL, 16, 64); dbL += __shfl_xor(dbL, 32, 64);
  if (quad == 0){
    atomicAdd(&cntP[row0 + l15], cpL);
    atomicAdd(&cntN[row0 + l15], cnL);
    atomicAdd(&denB[row0 + l15], dbL);
  }
}

// ---------------- fp64 boundary refinement + sparse fixup ----------------
__global__ void k_refine(const float* __restrict__ E, const double* __restrict__ nrm64,
    const ush* __restrict__ EhiT, const ush* __restrict__ EloT,
    const ush* __restrict__ VhT,  const ush* __restrict__ VloT,
    const int* __restrict__ flagCnt, const float4* __restrict__ flags,
    float* __restrict__ Psum, float* __restrict__ Nsum, float* __restrict__ Bsum,
    float* __restrict__ cntP, float* __restrict__ cntN, float* __restrict__ denB)
{
  int cnt = *flagCnt; if (cnt > FLAGCAP) cnt = FLAGCAP;
  int lane = threadIdx.x & 63;
  int gw = (blockIdx.x * blockDim.x + threadIdx.x) >> 6;
  int nw = (gridDim.x * blockDim.x) >> 6;
  for (int idx = gw; idx < cnt; idx += nw){
    float4 rec = flags[idx];
    int i = __float_as_int(rec.x), j = __float_as_int(rec.y);
    float c = rec.z, s = rec.w;
    float ei0 = E[i*DD + lane], ei1 = E[i*DD + 64 + lane];
    float ej0 = E[j*DD + lane], ej1 = E[j*DD + 64 + lane];
    double d = (double)ei0*(double)ej0 + (double)ei1*(double)ej1;
    #pragma unroll
    for (int m = 32; m; m >>= 1) d += __shfl_xor(d, m, 64);
    double se = d / (nrm64[i]*nrm64[j]);
    int ce = (se >= (double)ALPHA) ? 0 : ((se <= (double)BETA) ? 1 : 2);
    int cc = (c >= ALPHA) ? 0 : ((c <= BETA) ? 1 : 2);
    if (ce == cc) continue;
    float e = __expf(s);
    float ehf = bf2f(f2bf(e));
    float elf = bf2f(f2bf(e - ehf));
    #pragma unroll
    for (int h = 0; h < 2; h++){
      int dd2 = lane + h*64;
      float ev = bf2f(EhiT[(size_t)dd2*NN + j]) + bf2f(EloT[(size_t)dd2*NN + j]);
      float vh = bf2f(VhT[(size_t)dd2*NN + j]);
      float vl = bf2f(VloT[(size_t)dd2*NN + j]);
      float bv = ehf*vh + elf*vh + ehf*vl;
      float* subA = (cc==0) ? Psum : (cc==1) ? Nsum : Bsum;
      atomicAdd(&subA[i*DD + dd2], (cc==2) ? -bv : -ev);
      float* addA = (ce==0) ? Psum : (ce==1) ? Nsum : Bsum;
      atomicAdd(&addA[i*DD + dd2], (ce==2) ?  bv :  ev);
    }
    if (lane == 0){
      float* subC = (cc==0) ? cntP : (cc==1) ? cntN : denB;
      atomicAdd(&subC[i], (cc==2) ? -e : -1.f);
      float* addC = (ce==0) ? cntP : (ce==1) ? cntN : denB;
      atomicAdd(&addC[i], (ce==2) ?  e :  1.f);
    }
  }
}

extern "C" void kernel_launch(void* const* d_in, const int* in_sizes, int n_in,
                              void* d_out, int out_size, void* d_ws, size_t ws_size,
                              hipStream_t stream){
  const float* adj   = (const float*)d_in[0];
  const float* embed = (const float*)d_in[1];
  const float* gc_w  = (const float*)d_in[2];
  const float* gc_b  = (const float*)d_in[3];
  const float* wq = (const float*)d_in[4];
  const float* bq = (const float*)d_in[5];
  const float* wk = (const float*)d_in[6];
  const float* bk = (const float*)d_in[7];
  const float* wv = (const float*)d_in[8];
  const float* bv = (const float*)d_in[9];
  const float* g1w = (const float*)d_in[10];
  const float* g1b = (const float*)d_in[11];
  const float* g2w = (const float*)d_in[12];
  const float* g2b = (const float*)d_in[13];
  const float* lw  = (const float*)d_in[14];
  float* out = (float*)d_out;

  char* p = (char*)d_ws;
  auto alloc = [&](size_t bytes)->void*{ void* r = (void*)p; p += (bytes + 255) & ~(size_t)255; return r; };
  ush* qkvTh = (ush*)alloc(384*128*2);  ush* qkvTl = (ush*)alloc(384*128*2);
  ush* g1wTh = (ush*)alloc(512*256*2);  ush* g1wTl = (ush*)alloc(512*256*2);
  ush* gcwTh = (ush*)alloc(2*128*128*2); ush* gcwTl = (ush*)alloc(2*128*128*2);
  unsigned* adjw = (unsigned*)alloc((size_t)NN*256*4);
  double* nrm64 = (double*)alloc(NN*8);
  ush* Enh  = (ush*)alloc((size_t)NN*DD*2);
  ush* Enl  = (ush*)alloc((size_t)NN*DD*2);
  ush* EhiT = (ush*)alloc((size_t)NN*DD*2);
  ush* EloT = (ush*)alloc((size_t)NN*DD*2);
  ush* Qh   = (ush*)alloc((size_t)NN*DD*2);
  ush* Khb  = (ush*)alloc((size_t)NN*DD*2);
  ush* VhT  = (ush*)alloc((size_t)NN*DD*2);
  ush* VloT = (ush*)alloc((size_t)NN*DD*2);
  char* zbase = p;
  float* Psum = (float*)alloc((size_t)NN*DD*4);
  float* Nsum = (float*)alloc((size_t)NN*DD*4);
  float* Bsum = (float*)alloc((size_t)NN*DD*4);
  float* cntP = (float*)alloc(NN*4);
  float* cntN = (float*)alloc(NN*4);
  float* denB = (float*)alloc(NN*4);
  int*   flagCnt = (int*)alloc(256);
  size_t zbytes = (size_t)(p - zbase);
  float4* flags = (float4*)alloc((size_t)FLAGCAP*16);
  float* hbuf = (float*)alloc((size_t)NN*256*4);
  float* cur0 = (float*)alloc((size_t)NN*DD*4);

  // one-time prep (per call; inputs restored each replay)
  k_pack<<<NN, 256, 0, stream>>>(adj, adjw);
  k_transw_all<<<832, 256, 0, stream>>>(wq, wk, wv, g1w, gc_w,
      qkvTh, qkvTl, g1wTh, g1wTl, gcwTh, gcwTl);

  const float* Ecur = embed;
  for (int l = 0; l < 2; l++){
    k_prep<<<128, 256, 0, stream>>>(Ecur, nrm64, Enh, Enl, EhiT, EloT);
    k_qkv<<<256, 256, 0, stream>>>(Ecur, qkvTh, qkvTl, bq, bk, bv, Qh, Khb, VhT, VloT);
    hipMemsetAsync(zbase, 0, zbytes, stream);
    k_fused<<<512, 256, 0, stream>>>(adjw, Enh, Enl, Qh, Khb, EhiT, EloT, VhT, VloT,
        Psum, Nsum, Bsum, cntP, cntN, denB, flagCnt, flags);
    k_refine<<<512, 256, 0, stream>>>(Ecur, nrm64, EhiT, EloT, VhT, VloT, flagCnt, flags,
        Psum, Nsum, Bsum, cntP, cntN, denB);
    k_g1<<<256, 256, 0, stream>>>(Ecur, Psum, Bsum, Nsum, cntP, cntN, denB,
        g1wTh, g1wTl, g1b, hbuf);
    k_fusegc<<<256, 256, 0, stream>>>(Ecur, Psum, Bsum, Nsum, hbuf, g2w, g2b,
        cntP, cntN, denB, gcwTh + l*128*128, gcwTl + l*128*128, gc_b + l*128,
        cur0, lw, l, (l == 0) ? cur0 : out);
    Ecur = (l == 0) ? cur0 : out;
  }
}

// Round 9
// 1302.374 us; speedup vs baseline: 1.7200x; 1.7200x over previous
//
#include <hip/hip_runtime.h>
#include <stdint.h>

#define NN 8192
#define DD 128
#define ALPHA 0.7f
#define BETA 0.3f
#define LAM 0.1f
#define QSCALE 0.08838834764831845f  // 1/sqrt(128)
#define DELTA 3e-5f
#define FLAGCAP 262144

typedef __attribute__((ext_vector_type(8))) short short8;
typedef __attribute__((ext_vector_type(4))) float f32x4;
typedef unsigned short ush;

__device__ __forceinline__ ush f2bf(float f){
  union { float f; unsigned u; } v; v.f = f;
  return (ush)((v.u + 0x7FFFu + ((v.u >> 16) & 1u)) >> 16);
}
__device__ __forceinline__ float bf2f(ush s){
  union { unsigned u; float f; } v; v.u = ((unsigned)s) << 16; return v.f;
}

// ---------------- adjacency -> bitmask (one HBM pass; 8 MB output stays in L3) ----------------
__global__ void k_pack(const float* __restrict__ adj, unsigned* __restrict__ adjw){
  int i = blockIdx.x, wave = threadIdx.x >> 6, lane = threadIdx.x & 63;
  for (int seg = wave; seg < 128; seg += 4){
    int j = seg*64 + lane;
    unsigned long long bm = __ballot(adj[(size_t)i*NN + j] != 0.0f);
    if (lane == 0)  adjw[i*256 + seg*2]     = (unsigned)bm;
    if (lane == 32) adjw[i*256 + seg*2 + 1] = (unsigned)(bm >> 32);
  }
}

// ---------------- norms + normalized hi/lo split (4 rows/block) ----------------
__global__ void k_norm(const float* __restrict__ E, double* __restrict__ nrm64,
                       ush* __restrict__ Enh, ush* __restrict__ Enl){
  int i = blockIdx.x*4 + (threadIdx.x >> 6);
  int l = threadIdx.x & 63;
  float v0 = E[i*DD + l], v1 = E[i*DD + 64 + l];
  double ss = (double)v0*(double)v0 + (double)v1*(double)v1;
  #pragma unroll
  for (int m = 32; m; m >>= 1) ss += __shfl_xor(ss, m, 64);
  double nr = sqrt(ss); if (nr < 1e-8) nr = 1e-8;
  float inv = (float)(1.0 / nr);
  float n0 = v0*inv, n1 = v1*inv;
  ush h0 = f2bf(n0), h1 = f2bf(n1);
  Enh[i*DD + l] = h0;       Enh[i*DD + 64 + l] = h1;
  Enl[i*DD + l] = f2bf(n0 - bf2f(h0));
  Enl[i*DD + 64 + l] = f2bf(n1 - bf2f(h1));
  if (l == 0) nrm64[i] = nr;
}

// ---------------- fp32 [8192,128] -> hi/lo bf16 transposed [128,8192] ----------------
__global__ void k_transsplit(const float* __restrict__ in, ush* __restrict__ outH,
                             ush* __restrict__ outL){
  __shared__ float t[64][65];
  int r0 = blockIdx.x * 64, c0 = blockIdx.y * 64;
  for (int idx = threadIdx.x; idx < 4096; idx += 256){
    int r = idx >> 6, c = idx & 63;
    t[r][c] = in[(r0 + r)*DD + c0 + c];
  }
  __syncthreads();
  for (int idx = threadIdx.x; idx < 4096; idx += 256){
    int c = idx >> 6, r = idx & 63;
    float v = t[r][c];
    ush h = f2bf(v);
    outH[(size_t)(c0 + c)*NN + r0 + r] = h;
    outL[(size_t)(c0 + c)*NN + r0 + r] = f2bf(v - bf2f(h));
  }
}

// ---------------- all weight transposes+splits in one dispatch ----------------
__global__ void k_transw_all(const float* __restrict__ wq, const float* __restrict__ wk,
                             const float* __restrict__ wv, const float* __restrict__ g1w,
                             const float* __restrict__ gcw,
                             ush* __restrict__ qkvTh, ush* __restrict__ qkvTl,
                             ush* __restrict__ g1wTh, ush* __restrict__ g1wTl,
                             ush* __restrict__ gcwTh, ush* __restrict__ gcwTl){
  int idx = blockIdx.x*256 + threadIdx.x;
  const float* src; ush *dh, *dl; int K, Nout, li;
  if      (idx <  16384){ src=wq;        dh=qkvTh;        dl=qkvTl;        K=128; Nout=128; li=idx; }
  else if (idx <  32768){ src=wk;        dh=qkvTh+16384;  dl=qkvTl+16384;  K=128; Nout=128; li=idx-16384; }
  else if (idx <  49152){ src=wv;        dh=qkvTh+32768;  dl=qkvTl+32768;  K=128; Nout=128; li=idx-32768; }
  else if (idx < 180224){ src=g1w;       dh=g1wTh;        dl=g1wTl;        K=512; Nout=256; li=idx-49152; }
  else if (idx < 196608){ src=gcw;       dh=gcwTh;        dl=gcwTl;        K=128; Nout=128; li=idx-180224; }
  else if (idx < 212992){ src=gcw+16384; dh=gcwTh+16384;  dl=gcwTl+16384;  K=128; Nout=128; li=idx-196608; }
  else return;
  int k = li / Nout, n = li - k*Nout;
  float v = src[li];
  ush h = f2bf(v);
  dh[n*K + k] = h;
  dl[n*K + k] = f2bf(v - bf2f(h));
}

// ---------------- fused Q/K/V projection; V written transposed+split via LDS ----------------
__global__ void k_qkv(const float* __restrict__ A,
                      const ush* __restrict__ BtH, const ush* __restrict__ BtL,
                      const float* __restrict__ bq, const float* __restrict__ bk,
                      const float* __restrict__ bv,
                      ush* __restrict__ Qh, ush* __restrict__ Kh,
                      ush* __restrict__ VhT, ush* __restrict__ VloT){
  __shared__ float sV[128*33];
  int tid = threadIdx.x, lane = tid & 63, wave = tid >> 6;
  int l15 = lane & 15, quad = lane >> 4;
  int rowblk = blockIdx.x * 32;
  int row16 = rowblk + (wave >> 1)*16;
  int nf0 = (wave & 1)*12;
  f32x4 acc[12];
  #pragma unroll
  for (int i = 0; i < 12; i++){ f32x4 z = {0.f,0.f,0.f,0.f}; acc[i] = z; }
  #pragma unroll
  for (int kk = 0; kk < 4; kk++){
    const float* ap = &A[(row16 + l15)*DD + kk*32 + quad*8];
    short8 ah, al;
    #pragma unroll
    for (int j = 0; j < 8; j++){
      float v = ap[j];
      ush h = f2bf(v);
      ah[j] = (short)h; al[j] = (short)f2bf(v - bf2f(h));
    }
    #pragma unroll
    for (int i = 0; i < 12; i++){
      int bo = ((nf0 + i)*16 + l15)*DD + kk*32 + quad*8;
      short8 bh = *(const short8*)&BtH[bo];
      short8 bl = *(const short8*)&BtL[bo];
      acc[i] = __builtin_amdgcn_mfma_f32_16x16x32_bf16(ah, bh, acc[i], 0, 0, 0);
      acc[i] = __builtin_amdgcn_mfma_f32_16x16x32_bf16(al, bh, acc[i], 0, 0, 0);
      acc[i] = __builtin_amdgcn_mfma_f32_16x16x32_bf16(ah, bl, acc[i], 0, 0, 0);
    }
  }
  #pragma unroll
  for (int i = 0; i < 12; i++){
    int nfg = nf0 + i;
    int grp = nfg >> 3;
    int col = (nfg & 7)*16 + l15;
    float b = (grp == 0) ? bq[col] : (grp == 1) ? bk[col] : bv[col];
    #pragma unroll
    for (int r = 0; r < 4; r++){
      int row = row16 + quad*4 + r;
      float v = acc[i][r] + b;
      if (grp == 0)      Qh[row*DD + col] = f2bf(v * QSCALE);
      else if (grp == 1) Kh[row*DD + col] = f2bf(v);
      else               sV[col*33 + (row - rowblk)] = v;
    }
  }
  __syncthreads();
  int feat = tid >> 1, rh = (tid & 1)*16;
  ush hh[16], ll[16];
  #pragma unroll
  for (int j = 0; j < 16; j++){
    float v = sV[feat*33 + rh + j];
    ush h = f2bf(v);
    hh[j] = h; ll[j] = f2bf(v - bf2f(h));
  }
  size_t go = (size_t)feat*NN + rowblk + rh;
  *(uint4*)&VhT [go]     = *(const uint4*)&hh[0];
  *(uint4*)&VhT [go + 8] = *(const uint4*)&hh[8];
  *(uint4*)&VloT[go]     = *(const uint4*)&ll[0];
  *(uint4*)&VloT[go + 8] = *(const uint4*)&ll[8];
}

// ---------------- g1 GEMM with inline region scaling (512 blocks, 4-way nf split) ----------------
__global__ void k_g1(const float* __restrict__ E, const float* __restrict__ P,
                     const float* __restrict__ B, const float* __restrict__ N,
                     const float* __restrict__ cntP, const float* __restrict__ cntN,
                     const float* __restrict__ denB,
                     const ush* __restrict__ BtH, const ush* __restrict__ BtL,
                     const float* __restrict__ bias, float* __restrict__ out){
  int tid = threadIdx.x, lane = tid & 63, wave = tid >> 6;
  int l15 = lane & 15, quad = lane >> 4;
  int row16 = blockIdx.x*16;
  int nf0 = wave*4;
  int row = row16 + l15;
  float cp = cntP[row], cn = cntN[row], dn = denB[row];
  float rs[4] = {1.f, 1.f/fmaxf(cp,1.f), (dn > 0.5f) ? (1.f/dn) : 0.f, LAM/fmaxf(cn,1.f)};
  const float* bases[4] = {E, P, B, N};
  f32x4 acc[4];
  #pragma unroll
  for (int nf = 0; nf < 4; nf++){ f32x4 z = {0.f,0.f,0.f,0.f}; acc[nf] = z; }
  #pragma unroll
  for (int kk = 0; kk < 16; kk++){
    const float* ap = &bases[kk>>2][row*DD + (kk&3)*32 + quad*8];
    float sc = rs[kk>>2];
    short8 ah, al;
    #pragma unroll
    for (int j = 0; j < 8; j++){
      float v = ap[j] * sc;
      ush h = f2bf(v);
      ah[j] = (short)h; al[j] = (short)f2bf(v - bf2f(h));
    }
    #pragma unroll
    for (int nf = 0; nf < 4; nf++){
      int bo = ((nf0 + nf)*16 + l15)*512 + kk*32 + quad*8;
      short8 bh = *(const short8*)&BtH[bo];
      short8 bl = *(const short8*)&BtL[bo];
      acc[nf] = __builtin_amdgcn_mfma_f32_16x16x32_bf16(ah, bh, acc[nf], 0, 0, 0);
      acc[nf] = __builtin_amdgcn_mfma_f32_16x16x32_bf16(al, bh, acc[nf], 0, 0, 0);
      acc[nf] = __builtin_amdgcn_mfma_f32_16x16x32_bf16(ah, bl, acc[nf], 0, 0, 0);
    }
  }
  #pragma unroll
  for (int nf = 0; nf < 4; nf++){
    int col = (nf0 + nf)*16 + l15;
    float b = bias[col];
    #pragma unroll
    for (int r = 0; r < 4; r++){
      int rr = row16 + quad*4 + r;
      out[rr*256 + col] = fmaxf(acc[nf][r] + b, 0.f);
    }
  }
}

// ---------------- fused gate + fusion + gc GEMM (512 blocks, 2-nf waves; + final combine) ----------------
__global__ void k_fusegc(const float* __restrict__ E, const float* __restrict__ P,
                         const float* __restrict__ B, const float* __restrict__ N,
                         const float* __restrict__ hbuf, const float* __restrict__ g2w,
                         const float* __restrict__ g2b,
                         const float* __restrict__ cntP, const float* __restrict__ cntN,
                         const float* __restrict__ denB,
                         const ush* __restrict__ BtH, const ush* __restrict__ BtL,
                         const float* __restrict__ bias,
                         const float* __restrict__ prevC, const float* __restrict__ lwv,
                         int dofinal, float* __restrict__ out){
  int tid = threadIdx.x, lane = tid & 63, wave = tid >> 6;
  int l15 = lane & 15, quad = lane >> 4;
  int row16 = blockIdx.x*16;
  int nf0 = wave*2;
  int row = row16 + l15;
  float l0=0,l1=0,l2=0,l3=0;
  #pragma unroll
  for (int i = 0; i < 16; i++){
    float4 hv = *(const float4*)&hbuf[row*256 + quad*64 + i*4];
    float hvv[4] = {hv.x, hv.y, hv.z, hv.w};
    #pragma unroll
    for (int j = 0; j < 4; j++){
      float4 w4 = *(const float4*)&g2w[(quad*64 + i*4 + j)*4];
      l0 = fmaf(hvv[j], w4.x, l0); l1 = fmaf(hvv[j], w4.y, l1);
      l2 = fmaf(hvv[j], w4.z, l2); l3 = fmaf(hvv[j], w4.w, l3);
    }
  }
  l0 += __shfl_xor(l0,16,64); l0 += __shfl_xor(l0,32,64);
  l1 += __shfl_xor(l1,16,64); l1 += __shfl_xor(l1,32,64);
  l2 += __shfl_xor(l2,16,64); l2 += __shfl_xor(l2,32,64);
  l3 += __shfl_xor(l3,16,64); l3 += __shfl_xor(l3,32,64);
  l0 += g2b[0]; l1 += g2b[1]; l2 += g2b[2]; l3 += g2b[3];
  float mx = fmaxf(fmaxf(l0,l1), fmaxf(l2,l3));
  float e0 = __expf(l0-mx), e1 = __expf(l1-mx), e2 = __expf(l2-mx), e3 = __expf(l3-mx);
  float inv = 1.f/(e0+e1+e2+e3);
  float g0 = e0*inv, g1v = e1*inv, g2v = e2*inv, g3 = e3*inv;
  float cp = cntP[row], cn = cntN[row], dn = denB[row];
  bool any = (cp + cn > 0.5f) || (dn > 0.5f);
  float pscl = g1v/fmaxf(cp,1.f);
  float bscl = (dn > 0.5f) ? (g2v/dn) : 0.f;
  float nscl = LAM*g3/fmaxf(cn,1.f);
  f32x4 acc[2];
  #pragma unroll
  for (int nf = 0; nf < 2; nf++){ f32x4 z = {0.f,0.f,0.f,0.f}; acc[nf] = z; }
  #pragma unroll
  for (int kk = 0; kk < 4; kk++){
    int koff = row*DD + kk*32 + quad*8;
    short8 ah, al;
    #pragma unroll
    for (int j = 0; j < 8; j++){
      float ev = E[koff + j];
      float v = any ? (g0*ev + pscl*P[koff+j] + bscl*B[koff+j] + nscl*N[koff+j]) : ev;
      ush h = f2bf(v);
      ah[j] = (short)h; al[j] = (short)f2bf(v - bf2f(h));
    }
    #pragma unroll
    for (int nf = 0; nf < 2; nf++){
      int bo = ((nf0 + nf)*16 + l15)*DD + kk*32 + quad*8;
      short8 bh = *(const short8*)&BtH[bo];
      short8 bl = *(const short8*)&BtL[bo];
      acc[nf] = __builtin_amdgcn_mfma_f32_16x16x32_bf16(ah, bh, acc[nf], 0, 0, 0);
      acc[nf] = __builtin_amdgcn_mfma_f32_16x16x32_bf16(al, bh, acc[nf], 0, 0, 0);
      acc[nf] = __builtin_amdgcn_mfma_f32_16x16x32_bf16(ah, bl, acc[nf], 0, 0, 0);
    }
  }
  float we0 = 0.5f, we1 = 0.5f;
  if (dofinal){
    float a0 = lwv[0], a1 = lwv[1];
    float mw = fmaxf(a0, a1);
    float x0 = __expf(a0-mw), x1 = __expf(a1-mw);
    float iv = 1.f/(x0+x1);
    we0 = x0*iv; we1 = x1*iv;
  }
  #pragma unroll
  for (int nf = 0; nf < 2; nf++){
    int col = (nf0 + nf)*16 + l15;
    float b = bias[col];
    #pragma unroll
    for (int r = 0; r < 4; r++){
      int rr = row16 + quad*4 + r;
      float val = fmaxf(acc[nf][r] + b, 0.f);
      if (dofinal) val = we0*prevC[rr*DD + col] + we1*val;
      out[rr*DD + col] = val;
    }
  }
}

// ---------------- fused sim/classify/aggregate (R3/R6/R7 known-good; FROZEN) ----------------
#define BM 64
#define BN 32
#define CSPLIT 4
#define CCHUNK (NN/CSPLIT)
#define NTILES (CCHUNK/BN)
#define RSTRIDE 136
#define FSTRIDE 80
#define MSTRIDE 80

__launch_bounds__(256, 2)
__global__ void k_fused(const unsigned* __restrict__ adjw,
    const ush* __restrict__ Enh, const ush* __restrict__ Enl,
    const ush* __restrict__ Qh,  const ush* __restrict__ Kh,
    const ush* __restrict__ EhiT, const ush* __restrict__ EloT,
    const ush* __restrict__ VhT,  const ush* __restrict__ VloT,
    float* __restrict__ Psum, float* __restrict__ Nsum, float* __restrict__ Bsum,
    float* __restrict__ cntP, float* __restrict__ cntN, float* __restrict__ denB,
    int* __restrict__ flagCnt, float4* __restrict__ flags)
{
  __shared__ __attribute__((aligned(16))) ush sEnh[32*RSTRIDE];
  __shared__ __attribute__((aligned(16))) ush sEnl[32*RSTRIDE];
  __shared__ __attribute__((aligned(16))) ush sKh [32*RSTRIDE];
  __shared__ __attribute__((aligned(16))) ush sE2 [128*FSTRIDE];
  __shared__ __attribute__((aligned(16))) ush sV2 [128*FSTRIDE];
  __shared__ __attribute__((aligned(16))) ush sM  [4][16*MSTRIDE];

  int tid = threadIdx.x, lane = tid & 63, wave = tid >> 6;
  int l15 = lane & 15, quad = lane >> 4;
  int rowblk = blockIdx.x >> 2, split = blockIdx.x & 3;
  int row0 = rowblk * BM + wave * 16;
  int col0 = split * CCHUNK;

  short8 bEnh[4], bEnl[4], bQ[4];
  #pragma unroll
  for (int kf = 0; kf < 4; kf++){
    int go = (row0 + l15)*DD + kf*32 + quad*8;
    bEnh[kf] = *(const short8*)&Enh[go];
    bEnl[kf] = *(const short8*)&Enl[go];
    bQ  [kf] = *(const short8*)&Qh [go];
  }

  f32x4 accP[8], accN[8], accB[8];
  #pragma unroll
  for (int nf = 0; nf < 8; nf++){ f32x4 z = {0.f,0.f,0.f,0.f}; accP[nf]=z; accN[nf]=z; accB[nf]=z; }
  float cpL = 0.f, cnL = 0.f, dbL = 0.f;

  int f0 = tid >> 2,        n0 = (tid & 3)*8;
  int f1 = (tid+256) >> 2,  n1 = ((tid+256) & 3)*8;
  uint4 pEh0, pEh1, pEl0, pEl1, pVh0, pVh1, pVl0, pVl1;
  {
    size_t g0 = (size_t)f0*NN + col0 + n0, g1 = (size_t)f1*NN + col0 + n1;
    pEh0 = *(const uint4*)&EhiT[g0]; pEh1 = *(const uint4*)&EhiT[g1];
    pEl0 = *(const uint4*)&EloT[g0]; pEl1 = *(const uint4*)&EloT[g1];
    pVh0 = *(const uint4*)&VhT [g0]; pVh1 = *(const uint4*)&VhT [g1];
    pVl0 = *(const uint4*)&VloT[g0]; pVl1 = *(const uint4*)&VloT[g1];
  }
  int rr0 = tid >> 4,       ro0 = (tid & 15)*8;
  int rr1 = (tid+256) >> 4, ro1 = ((tid+256) & 15)*8;

  for (int t = 0; t < NTILES; t++){
    int c0 = col0 + t*BN;
    __syncthreads();
    *(uint4*)&sE2[f0*FSTRIDE + n0]      = pEh0;  *(uint4*)&sE2[f1*FSTRIDE + n1]      = pEh1;
    *(uint4*)&sE2[f0*FSTRIDE + 40 + n0] = pEl0;  *(uint4*)&sE2[f1*FSTRIDE + 40 + n1] = pEl1;
    *(uint4*)&sV2[f0*FSTRIDE + n0]      = pVh0;  *(uint4*)&sV2[f1*FSTRIDE + n1]      = pVh1;
    *(uint4*)&sV2[f0*FSTRIDE + 40 + n0] = pVl0;  *(uint4*)&sV2[f1*FSTRIDE + 40 + n1] = pVl1;
    {
      uint4 a0 = *(const uint4*)&Enh[(c0 + rr0)*DD + ro0];
      uint4 a1 = *(const uint4*)&Enh[(c0 + rr1)*DD + ro1];
      uint4 b0 = *(const uint4*)&Enl[(c0 + rr0)*DD + ro0];
      uint4 b1 = *(const uint4*)&Enl[(c0 + rr1)*DD + ro1];
      uint4 k0 = *(const uint4*)&Kh [(c0 + rr0)*DD + ro0];
      uint4 k1 = *(const uint4*)&Kh [(c0 + rr1)*DD + ro1];
      *(uint4*)&sEnh[rr0*RSTRIDE + ro0] = a0;  *(uint4*)&sEnh[rr1*RSTRIDE + ro1] = a1;
      *(uint4*)&sEnl[rr0*RSTRIDE + ro0] = b0;  *(uint4*)&sEnl[rr1*RSTRIDE + ro1] = b1;
      *(uint4*)&sKh [rr0*RSTRIDE + ro0] = k0;  *(uint4*)&sKh [rr1*RSTRIDE + ro1] = k1;
    }
    __syncthreads();
    if (t + 1 < NTILES){
      int c1 = c0 + BN;
      size_t g0 = (size_t)f0*NN + c1 + n0, g1 = (size_t)f1*NN + c1 + n1;
      pEh0 = *(const uint4*)&EhiT[g0]; pEh1 = *(const uint4*)&EhiT[g1];
      pEl0 = *(const uint4*)&EloT[g0]; pEl1 = *(const uint4*)&EloT[g1];
      pVh0 = *(const uint4*)&VhT [g0]; pVh1 = *(const uint4*)&VhT [g1];
      pVl0 = *(const uint4*)&VloT[g0]; pVl1 = *(const uint4*)&VloT[g1];
    }
    unsigned aw = adjw[(row0 + l15)*256 + (c0 >> 5)];

    f32x4 simT[2], svT[2];
    { f32x4 z = {0.f,0.f,0.f,0.f}; simT[0]=z; simT[1]=z; svT[0]=z; svT[1]=z; }
    #pragma unroll
    for (int f = 0; f < 2; f++){
      #pragma unroll
      for (int kf = 0; kf < 4; kf++){
        int la = (f*16 + l15)*RSTRIDE + kf*32 + quad*8;
        short8 ch = *(const short8*)&sEnh[la];
        short8 cl = *(const short8*)&sEnl[la];
        short8 ck = *(const short8*)&sKh [la];
        simT[f] = __builtin_amdgcn_mfma_f32_16x16x32_bf16(ch, bEnh[kf], simT[f],0,0,0);
        simT[f] = __builtin_amdgcn_mfma_f32_16x16x32_bf16(cl, bEnh[kf], simT[f],0,0,0);
        simT[f] = __builtin_amdgcn_mfma_f32_16x16x32_bf16(ch, bEnl[kf], simT[f],0,0,0);
        svT [f] = __builtin_amdgcn_mfma_f32_16x16x32_bf16(ck, bQ  [kf], svT [f],0,0,0);
      }
    }
    ushort4 ehv[2], elv[2];
    unsigned flagb = 0;
    #pragma unroll
    for (int f = 0; f < 2; f++){
      ush vp[4], vn2[4], veh[4], vel[4];
      #pragma unroll
      for (int r = 0; r < 4; r++){
        int cbit = f*16 + quad*4 + r;
        bool nbr = (aw >> cbit) & 1u;
        float c = simT[f][r], s = svT[f][r];
        bool pos = nbr && (c >= ALPHA);
        bool neg = nbr && (c <= BETA);
        bool bnd = nbr && !pos && !neg;
        float e = bnd ? __expf(s) : 0.f;
        ush eh = f2bf(e);
        vp[r]  = pos ? (ush)0x3F80 : (ush)0;
        vn2[r] = neg ? (ush)0x3F80 : (ush)0;
        veh[r] = eh;
        vel[r] = f2bf(e - bf2f(eh));
        cpL += pos ? 1.f : 0.f;
        cnL += neg ? 1.f : 0.f;
        dbL += e;
        if (nbr && (fabsf(c - ALPHA) < DELTA || fabsf(c - BETA) < DELTA))
          flagb |= 1u << (f*4 + r);
      }
      int mb = l15*MSTRIDE + f*16 + quad*4;
      *(ushort4*)&sM[wave][mb]      = make_ushort4(vp[0],vp[1],vp[2],vp[3]);
      *(ushort4*)&sM[wave][mb + 40] = make_ushort4(vn2[0],vn2[1],vn2[2],vn2[3]);
      ehv[f] = make_ushort4(veh[0],veh[1],veh[2],veh[3]);
      elv[f] = make_ushort4(vel[0],vel[1],vel[2],vel[3]);
    }
    if (__ballot(flagb != 0)){
      #pragma unroll
      for (int f = 0; f < 2; f++){
        #pragma unroll
        for (int r = 0; r < 4; r++){
          bool fl = (flagb >> (f*4 + r)) & 1u;
          unsigned long long bm = __ballot(fl);
          if (bm){
            int leader = __ffsll((long long)bm) - 1;
            int base = 0;
            if (lane == leader) base = atomicAdd(flagCnt, __popcll(bm));
            base = __shfl(base, leader, 64);
            if (fl){
              int id = base + __popcll(bm & ((1ull << lane) - 1ull));
              if (id < FLAGCAP){
                float4 rec;
                rec.x = __int_as_float(row0 + l15);
                rec.y = __int_as_float(c0 + f*16 + quad*4 + r);
                rec.z = simT[f][r]; rec.w = svT[f][r];
                flags[id] = rec;
              }
            }
          }
        }
      }
    }
    {
      short8 mPos = *(const short8*)&sM[wave][l15*MSTRIDE + quad*8];
      short8 mNeg = *(const short8*)&sM[wave][l15*MSTRIDE + 40 + quad*8];
      #pragma unroll
      for (int nf = 0; nf < 8; nf++){
        int so = (nf*16 + l15)*FSTRIDE + quad*8;
        short8 eth = *(const short8*)&sE2[so];
        short8 etl = *(const short8*)&sE2[so + 40];
        accP[nf] = __builtin_amdgcn_mfma_f32_16x16x32_bf16(mPos, eth, accP[nf],0,0,0);
        accP[nf] = __builtin_amdgcn_mfma_f32_16x16x32_bf16(mPos, etl, accP[nf],0,0,0);
        accN[nf] = __builtin_amdgcn_mfma_f32_16x16x32_bf16(mNeg, eth, accN[nf],0,0,0);
        accN[nf] = __builtin_amdgcn_mfma_f32_16x16x32_bf16(mNeg, etl, accN[nf],0,0,0);
      }
    }
    {
      int mb0 = l15*MSTRIDE + quad*4;
      *(ushort4*)&sM[wave][mb0]           = ehv[0];
      *(ushort4*)&sM[wave][mb0 + 16]      = ehv[1];
      *(ushort4*)&sM[wave][mb0 + 40]      = elv[0];
      *(ushort4*)&sM[wave][mb0 + 40 + 16] = elv[1];
      short8 mEh = *(const short8*)&sM[wave][l15*MSTRIDE + quad*8];
      short8 mEl = *(const short8*)&sM[wave][l15*MSTRIDE + 40 + quad*8];
      #pragma unroll
      for (int nf = 0; nf < 8; nf++){
        int so = (nf*16 + l15)*FSTRIDE + quad*8;
        short8 vth = *(const short8*)&sV2[so];
        short8 vtl = *(const short8*)&sV2[so + 40];
        accB[nf] = __builtin_amdgcn_mfma_f32_16x16x32_bf16(mEh, vth, accB[nf],0,0,0);
        accB[nf] = __builtin_amdgcn_mfma_f32_16x16x32_bf16(mEl, vth, accB[nf],0,0,0);
        accB[nf] = __builtin_amdgcn_mfma_f32_16x16x32_bf16(mEh, vtl, accB[nf],0,0,0);
      }
    }
  }
  #pragma unroll
  for (int nf = 0; nf < 8; nf++){
    int col = nf*16 + l15;
    #pragma unroll
    for (int r = 0; r < 4; r++){
      int row = row0 + quad*4 + r;
      atomicAdd(&Psum[row*DD + col], accP[nf][r]);
      atomicAdd(&Nsum[row*DD + col], accN[nf][r]);
      atomicAdd(&Bsum[row*DD + col], accB[nf][r]);
    }
  }
  cpL += __shfl_xor(cpL, 16, 64); cpL += __shfl_xor(cpL, 32, 64);
  cnL += __shfl_xor(cnL, 16, 64); cnL += __shfl_xor(cnL, 32, 64);
  dbL += __shfl_xor(dbL, 16, 64); dbL += __shfl_xor(dbL, 32, 64);
  if (quad == 0){
    atomicAdd(&cntP[row0 + l15], cpL);
    atomicAdd(&cntN[row0 + l15], cnL);
    atomicAdd(&denB[row0 + l15], dbL);
  }
}

// ---------------- fp64 boundary refinement + sparse fixup ----------------
__global__ void k_refine(const float* __restrict__ E, const double* __restrict__ nrm64,
    const ush* __restrict__ EhiT, const ush* __restrict__ EloT,
    const ush* __restrict__ VhT,  const ush* __restrict__ VloT,
    const int* __restrict__ flagCnt, const float4* __restrict__ flags,
    float* __restrict__ Psum, float* __restrict__ Nsum, float* __restrict__ Bsum,
    float* __restrict__ cntP, float* __restrict__ cntN, float* __restrict__ denB)
{
  int cnt = *flagCnt; if (cnt > FLAGCAP) cnt = FLAGCAP;
  int lane = threadIdx.x & 63;
  int gw = (blockIdx.x * blockDim.x + threadIdx.x) >> 6;
  int nw = (gridDim.x * blockDim.x) >> 6;
  for (int idx = gw; idx < cnt; idx += nw){
    float4 rec = flags[idx];
    int i = __float_as_int(rec.x), j = __float_as_int(rec.y);
    float c = rec.z, s = rec.w;
    float ei0 = E[i*DD + lane], ei1 = E[i*DD + 64 + lane];
    float ej0 = E[j*DD + lane], ej1 = E[j*DD + 64 + lane];
    double d = (double)ei0*(double)ej0 + (double)ei1*(double)ej1;
    #pragma unroll
    for (int m = 32; m; m >>= 1) d += __shfl_xor(d, m, 64);
    double se = d / (nrm64[i]*nrm64[j]);
    int ce = (se >= (double)ALPHA) ? 0 : ((se <= (double)BETA) ? 1 : 2);
    int cc = (c >= ALPHA) ? 0 : ((c <= BETA) ? 1 : 2);
    if (ce == cc) continue;
    float e = __expf(s);
    float ehf = bf2f(f2bf(e));
    float elf = bf2f(f2bf(e - ehf));
    #pragma unroll
    for (int h = 0; h < 2; h++){
      int dd2 = lane + h*64;
      float ev = bf2f(EhiT[(size_t)dd2*NN + j]) + bf2f(EloT[(size_t)dd2*NN + j]);
      float vh = bf2f(VhT[(size_t)dd2*NN + j]);
      float vl = bf2f(VloT[(size_t)dd2*NN + j]);
      float bv = ehf*vh + elf*vh + ehf*vl;
      float* subA = (cc==0) ? Psum : (cc==1) ? Nsum : Bsum;
      atomicAdd(&subA[i*DD + dd2], (cc==2) ? -bv : -ev);
      float* addA = (ce==0) ? Psum : (ce==1) ? Nsum : Bsum;
      atomicAdd(&addA[i*DD + dd2], (ce==2) ?  bv :  ev);
    }
    if (lane == 0){
      float* subC = (cc==0) ? cntP : (cc==1) ? cntN : denB;
      atomicAdd(&subC[i], (cc==2) ? -e : -1.f);
      float* addC = (ce==0) ? cntP : (ce==1) ? cntN : denB;
      atomicAdd(&addC[i], (ce==2) ?  e :  1.f);
    }
  }
}

extern "C" void kernel_launch(void* const* d_in, const int* in_sizes, int n_in,
                              void* d_out, int out_size, void* d_ws, size_t ws_size,
                              hipStream_t stream){
  const float* adj   = (const float*)d_in[0];
  const float* embed = (const float*)d_in[1];
  const float* gc_w  = (const float*)d_in[2];
  const float* gc_b  = (const float*)d_in[3];
  const float* wq = (const float*)d_in[4];
  const float* bq = (const float*)d_in[5];
  const float* wk = (const float*)d_in[6];
  const float* bk = (const float*)d_in[7];
  const float* wv = (const float*)d_in[8];
  const float* bv = (const float*)d_in[9];
  const float* g1w = (const float*)d_in[10];
  const float* g1b = (const float*)d_in[11];
  const float* g2w = (const float*)d_in[12];
  const float* g2b = (const float*)d_in[13];
  const float* lw  = (const float*)d_in[14];
  float* out = (float*)d_out;

  char* p = (char*)d_ws;
  auto alloc = [&](size_t bytes)->void*{ void* r = (void*)p; p += (bytes + 255) & ~(size_t)255; return r; };
  ush* qkvTh = (ush*)alloc(384*128*2);  ush* qkvTl = (ush*)alloc(384*128*2);
  ush* g1wTh = (ush*)alloc(512*256*2);  ush* g1wTl = (ush*)alloc(512*256*2);
  ush* gcwTh = (ush*)alloc(2*128*128*2); ush* gcwTl = (ush*)alloc(2*128*128*2);
  unsigned* adjw = (unsigned*)alloc((size_t)NN*256*4);
  double* nrm64 = (double*)alloc(NN*8);
  ush* Enh  = (ush*)alloc((size_t)NN*DD*2);
  ush* Enl  = (ush*)alloc((size_t)NN*DD*2);
  ush* EhiT = (ush*)alloc((size_t)NN*DD*2);
  ush* EloT = (ush*)alloc((size_t)NN*DD*2);
  ush* Qh   = (ush*)alloc((size_t)NN*DD*2);
  ush* Khb  = (ush*)alloc((size_t)NN*DD*2);
  ush* VhT  = (ush*)alloc((size_t)NN*DD*2);
  ush* VloT = (ush*)alloc((size_t)NN*DD*2);
  char* zbase = p;
  float* Psum = (float*)alloc((size_t)NN*DD*4);
  float* Nsum = (float*)alloc((size_t)NN*DD*4);
  float* Bsum = (float*)alloc((size_t)NN*DD*4);
  float* cntP = (float*)alloc(NN*4);
  float* cntN = (float*)alloc(NN*4);
  float* denB = (float*)alloc(NN*4);
  int*   flagCnt = (int*)alloc(256);
  size_t zbytes = (size_t)(p - zbase);
  float4* flags = (float4*)alloc((size_t)FLAGCAP*16);
  float* hbuf = (float*)alloc((size_t)NN*256*4);
  float* cur0 = (float*)alloc((size_t)NN*DD*4);

  // one-time prep (per call; inputs restored each replay)
  k_pack<<<NN, 256, 0, stream>>>(adj, adjw);
  k_transw_all<<<832, 256, 0, stream>>>(wq, wk, wv, g1w, gc_w,
      qkvTh, qkvTl, g1wTh, g1wTl, gcwTh, gcwTl);

  const float* Ecur = embed;
  for (int l = 0; l < 2; l++){
    k_norm<<<2048, 256, 0, stream>>>(Ecur, nrm64, Enh, Enl);
    k_transsplit<<<dim3(128,2), 256, 0, stream>>>(Ecur, EhiT, EloT);
    k_qkv<<<256, 256, 0, stream>>>(Ecur, qkvTh, qkvTl, bq, bk, bv, Qh, Khb, VhT, VloT);
    hipMemsetAsync(zbase, 0, zbytes, stream);
    k_fused<<<512, 256, 0, stream>>>(adjw, Enh, Enl, Qh, Khb, EhiT, EloT, VhT, VloT,
        Psum, Nsum, Bsum, cntP, cntN, denB, flagCnt, flags);
    k_refine<<<512, 256, 0, stream>>>(Ecur, nrm64, EhiT, EloT, VhT, VloT, flagCnt, flags,
        Psum, Nsum, Bsum, cntP, cntN, denB);
    k_g1<<<512, 256, 0, stream>>>(Ecur, Psum, Bsum, Nsum, cntP, cntN, denB,
        g1wTh, g1wTl, g1b, hbuf);
    k_fusegc<<<512, 256, 0, stream>>>(Ecur, Psum, Bsum, Nsum, hbuf, g2w, g2b,
        cntP, cntN, denB, gcwTh + l*128*128, gcwTl + l*128*128, gc_b + l*128,
        cur0, lw, l, (l == 0) ? cur0 : out);
    Ecur = (l == 0) ? cur0 : out;
  }
}